// Round 18
// baseline (334.933 us; speedup 1.0000x reference)
//
#include <hip/hip_runtime.h>
#include <math.h>

#define N_NODES 50000
#define D 128
#define LAYERS 3
#define DZ 384
#define DOUT 40
#define BUCKETS 196          // ceil(50000/256)
#define BR 32                // rows per block in fused kernels
#define ADJ_LDS 2048         // staged adj entries per block (u16)

typedef __attribute__((ext_vector_type(4))) float f32x4;
typedef __attribute__((ext_vector_type(8))) short short8;

static __device__ __forceinline__ unsigned short f2bf(float f) {
    unsigned int u = __float_as_uint(f);
    u += 0x7FFFu + ((u >> 16) & 1u);
    return (unsigned short)(u >> 16);
}
static __device__ __forceinline__ float bflo(unsigned int u) {
    return __uint_as_float(u << 16);
}
static __device__ __forceinline__ float bfhi(unsigned int u) {
    return __uint_as_float(u & 0xFFFF0000u);
}
static __device__ __forceinline__ void accq(float* acc, uint4 q, float wgt) {
    acc[0] = fmaf(wgt, bflo(q.x), acc[0]);
    acc[1] = fmaf(wgt, bfhi(q.x), acc[1]);
    acc[2] = fmaf(wgt, bflo(q.y), acc[2]);
    acc[3] = fmaf(wgt, bfhi(q.y), acc[3]);
    acc[4] = fmaf(wgt, bflo(q.z), acc[4]);
    acc[5] = fmaf(wgt, bfhi(q.z), acc[5]);
    acc[6] = fmaf(wgt, bflo(q.w), acc[6]);
    acc[7] = fmaf(wgt, bfhi(q.w), acc[7]);
}

// ---------------- CSR build: atomic-free counting sort (dst only) ----------------

__global__ __launch_bounds__(256) void hist1_kernel(const int* __restrict__ dst, int E, int CH,
                                                    int nblk1, int* __restrict__ H) {
    __shared__ int h[BUCKETS];
    int t = threadIdx.x;
    if (t < BUCKETS) h[t] = 0;
    __syncthreads();
    int s = blockIdx.x * CH, e = min(E, s + CH);
    for (int i = s + t; i < e; i += 256) atomicAdd(&h[dst[i] >> 8], 1);
    __syncthreads();
    if (t < BUCKETS) H[t * nblk1 + blockIdx.x] = h[t];
}

__global__ __launch_bounds__(512) void scanS_kernel(int* __restrict__ H, int nblk1,
                                                    int* __restrict__ T) {
    __shared__ int s[512];
    int t = threadIdx.x, k = blockIdx.x;
    int v = (t < nblk1) ? H[k * nblk1 + t] : 0;
    s[t] = v;
    __syncthreads();
    for (int off = 1; off < 512; off <<= 1) {
        int u = (t >= off) ? s[t - off] : 0;
        __syncthreads();
        s[t] += u;
        __syncthreads();
    }
    if (t < nblk1) H[k * nblk1 + t] = s[t] - v;
    if (t == 511) T[k] = s[511];
}

__global__ __launch_bounds__(256) void bstart_kernel(const int* __restrict__ T,
                                                     int* __restrict__ bucketStart,
                                                     int* __restrict__ offs, int E) {
    __shared__ int s[256];
    int t = threadIdx.x;
    int v = (t < BUCKETS) ? T[t] : 0;
    s[t] = v;
    __syncthreads();
    for (int off = 1; off < 256; off <<= 1) {
        int u = (t >= off) ? s[t - off] : 0;
        __syncthreads();
        s[t] += u;
        __syncthreads();
    }
    if (t < BUCKETS) bucketStart[t] = s[t] - v;
    if (t == 0) { bucketStart[BUCKETS] = E; offs[N_NODES] = E; }
}

__global__ __launch_bounds__(256) void scatter_kernel(const int* __restrict__ src,
                                                      const int* __restrict__ dst, int E, int CH,
                                                      int nblk1, const int* __restrict__ H,
                                                      const int* __restrict__ bucketStart,
                                                      unsigned int* __restrict__ recs) {
    __shared__ int cur[BUCKETS];
    int t = threadIdx.x;
    if (t < BUCKETS) cur[t] = bucketStart[t] + H[t * nblk1 + blockIdx.x];
    __syncthreads();
    int s = blockIdx.x * CH, e = min(E, s + CH);
    for (int i = s + t; i < e; i += 256) {
        int d = dst[i];
        int pos = atomicAdd(&cur[d >> 8], 1);
        recs[pos] = (unsigned int)(src[i] & 0xFFFF) | ((unsigned int)(d & 255) << 16);
    }
}

__global__ __launch_bounds__(256) void bucket_csr_kernel(const unsigned int* __restrict__ recs,
                                                         const int* __restrict__ bucketStart,
                                                         int* __restrict__ offs,
                                                         unsigned short* __restrict__ adj) {
    __shared__ int h[256];
    __shared__ int sc[256];
    __shared__ int cur[256];
    int t = threadIdx.x, k = blockIdx.x;
    int bs = bucketStart[k], be = bucketStart[k + 1];
    h[t] = 0;
    __syncthreads();
    for (int i = bs + t; i < be; i += 256) atomicAdd(&h[(recs[i] >> 16) & 255], 1);
    __syncthreads();
    int v = h[t];
    sc[t] = v;
    __syncthreads();
    for (int off = 1; off < 256; off <<= 1) {
        int u = (t >= off) ? sc[t - off] : 0;
        __syncthreads();
        sc[t] += u;
        __syncthreads();
    }
    int excl = sc[t] - v;
    int node = k * 256 + t;
    if (node < N_NODES) offs[node] = bs + excl;
    cur[t] = bs + excl;
    __syncthreads();
    for (int i = bs + t; i < be; i += 256) {
        unsigned int r = recs[i];
        int pos = atomicAdd(&cur[(r >> 16) & 255], 1);
        adj[pos] = (unsigned short)(r & 0xFFFF);
    }
}

// ---------------- fused conversions + weight packing ----------------

__global__ __launch_bounds__(256) void prep_kernel(const float* __restrict__ x,
                                                   const float* __restrict__ Wl,
                                                   const float* __restrict__ Wr,
                                                   const float* __restrict__ W1,
                                                   const float* __restrict__ W2,
                                                   unsigned short* __restrict__ xb,
                                                   unsigned short* __restrict__ WT,
                                                   unsigned short* __restrict__ W1T,
                                                   unsigned short* __restrict__ W2T,
                                                   int n4) {
    int i = blockIdx.x * blockDim.x + threadIdx.x;
    if (i < n4) {
        const float4 v = ((const float4*)x)[i];
        unsigned int lo = ((unsigned int)f2bf(v.y) << 16) | f2bf(v.x);
        unsigned int hi = ((unsigned int)f2bf(v.w) << 16) | f2bf(v.z);
        ((unsigned int*)xb)[i * 2] = lo;
        ((unsigned int*)xb)[i * 2 + 1] = hi;
        return;
    }
    int j = i - n4;
    if (j < LAYERS * 128 * 256) {
        int layer = j >> 15;
        int r = j & 32767;
        int c = r >> 8, k = r & 255;
        const float* W = (k < 128) ? (Wl + layer * 16384) : (Wr + layer * 16384);
        WT[j] = f2bf(W[(k & 127) * 128 + c]);
        return;
    }
    j -= LAYERS * 128 * 256;
    if (j < 128 * 384) {
        int c = j / 384, k = j - c * 384;
        W1T[j] = f2bf(W1[k * 128 + c]);
        return;
    }
    j -= 128 * 384;
    if (j < 48 * 128) {
        int c = j >> 7, k = j & 127;
        W2T[j] = (c < DOUT) ? f2bf(W2[k * DOUT + c]) : (unsigned short)0;
    }
}

// ---------------- fused mean-aggregate + SAGE GEMM (512 threads = 8 waves) ----------------
// Phase 0: stage own h-rows, adj segment, offs[33]; zero fp32 accum buffer.
// Phase 1: EDGE-BALANCED gather: block's edge segment split into 32 equal
//          chunks (one per 16-lane group); register accum, LDS fp32 atomic
//          flush at node boundaries. No straggler groups.
// Phase 2: 8 waves x 16-col stripes; A from LDS, B (WT) in-loop from L2.
__global__ __launch_bounds__(512) void sage_fused_kernel(
        const unsigned short* __restrict__ h,    // [N,128] prev-layer features
        const int* __restrict__ offs, const unsigned short* __restrict__ adj,
        const unsigned short* __restrict__ WT,   // [128][256]
        const float* __restrict__ bl,
        unsigned short* __restrict__ zout) {     // [N,128]
    __shared__ unsigned short mlds[BR][136];
    __shared__ unsigned short hlds[BR][136];
    __shared__ unsigned short adjlds[ADJ_LDS];
    __shared__ float macc[BR][132];
    __shared__ int offsl[BR + 1];
    int tid = threadIdx.x;
    int r0 = blockIdx.x * BR;
    int gid = tid >> 4, l16 = tid & 15;

    // ---- phase 0a: stage own rows (512 x 16B chunks, exactly 1 per thread)
    {
        int row = tid >> 4, c8 = (tid & 15) * 8;
        int rc = min(r0 + row, N_NODES - 1);
        *(uint4*)(&hlds[row][c8]) = *(const uint4*)(h + (size_t)rc * D + c8);
    }
    // ---- phase 0b: offs + zero macc + stage adj segment
    if (tid <= BR) offsl[tid] = offs[min(r0 + tid, N_NODES)];
    {
        float* mf = &macc[0][0];
        for (int i = tid; i < BR * 132; i += 512) mf[i] = 0.f;
    }
    __syncthreads();
    int segS = offsl[0];
    int segLen = offsl[BR] - segS;
    int staged = min(segLen, ADJ_LDS);
    for (int i = tid; i < staged; i += 512) adjlds[i] = adj[segS + i];
    __syncthreads();

    // ---- phase 1: edge-balanced gather
    {
        const unsigned short* hb = h + l16 * 8;
        int chunk = (segLen + BR - 1) / BR;
        int c0 = gid * chunk;
        int c1 = min(c0 + chunk, segLen);
        if (c0 < c1) {
            // starting node: largest n with offsl[n]-segS <= c0
            int node = 0;
            while (node < BR - 1 && offsl[node + 1] - segS <= c0) node++;
            int bnd = offsl[node + 1] - segS;
            float acc[8];
#pragma unroll
            for (int j = 0; j < 8; ++j) acc[j] = 0.f;
            bool dirty = false;

            for (int k = c0; k < c1; k += 8) {
                int a[8];
#pragma unroll
                for (int j = 0; j < 8; ++j) {
                    int kk = min(k + j, c1 - 1);
                    a[j] = (kk < staged) ? (int)adjlds[kk] : (int)adj[segS + kk];
                }
                uint4 q[8];
#pragma unroll
                for (int j = 0; j < 8; ++j) q[j] = *(const uint4*)(hb + (size_t)a[j] * D);
#pragma unroll
                for (int j = 0; j < 8; ++j) {
                    int kj = k + j;
                    if (kj < c1) {
                        while (kj >= bnd) {
                            if (dirty) {
#pragma unroll
                                for (int jj = 0; jj < 8; ++jj) {
                                    atomicAdd(&macc[node][l16 * 8 + jj], acc[jj]);
                                    acc[jj] = 0.f;
                                }
                                dirty = false;
                            }
                            node++;
                            bnd = offsl[node + 1] - segS;
                        }
                        accq(acc, q[j], 1.f);
                        dirty = true;
                    }
                }
            }
            if (dirty) {
#pragma unroll
                for (int jj = 0; jj < 8; ++jj)
                    atomicAdd(&macc[node][l16 * 8 + jj], acc[jj]);
            }
        }
    }
    __syncthreads();

    // ---- phase 1.5: means -> mlds (512 threads, 8 elems each)
    {
        int row = tid >> 4, c8 = (tid & 15) * 8;
        int deg = offsl[row + 1] - offsl[row];
        float inv = 1.f / fmaxf((float)deg, 1.f);
        uint4 o;
        o.x = ((unsigned int)f2bf(macc[row][c8 + 1] * inv) << 16) | f2bf(macc[row][c8 + 0] * inv);
        o.y = ((unsigned int)f2bf(macc[row][c8 + 3] * inv) << 16) | f2bf(macc[row][c8 + 2] * inv);
        o.z = ((unsigned int)f2bf(macc[row][c8 + 5] * inv) << 16) | f2bf(macc[row][c8 + 4] * inv);
        o.w = ((unsigned int)f2bf(macc[row][c8 + 7] * inv) << 16) | f2bf(macc[row][c8 + 6] * inv);
        *(uint4*)(&mlds[row][c8]) = o;
    }
    __syncthreads();

    // ---- phase 2: GEMM. 8 waves, wave cols [wid*16, wid*16+16)
    int wid = tid >> 6;
    int lane = tid & 63;
    int lrow = lane & 15;
    int lk8 = (lane >> 4) * 8;
    int colBase = wid * 16;
    f32x4 acc0 = (f32x4){0.f,0.f,0.f,0.f};
    f32x4 acc1 = (f32x4){0.f,0.f,0.f,0.f};

#pragma unroll
    for (int kc = 0; kc < 8; ++kc) {
        short8 aF0, aF1;
        if (kc < 4) {
            aF0 = *(const short8*)(&mlds[lrow][kc * 32 + lk8]);
            aF1 = *(const short8*)(&mlds[16 + lrow][kc * 32 + lk8]);
        } else {
            aF0 = *(const short8*)(&hlds[lrow][(kc - 4) * 32 + lk8]);
            aF1 = *(const short8*)(&hlds[16 + lrow][(kc - 4) * 32 + lk8]);
        }
        short8 bF = *(const short8*)(WT + (size_t)(colBase + lrow) * 256 + kc * 32 + lk8);
        acc0 = __builtin_amdgcn_mfma_f32_16x16x32_bf16(aF0, bF, acc0, 0, 0, 0);
        acc1 = __builtin_amdgcn_mfma_f32_16x16x32_bf16(aF1, bF, acc1, 0, 0, 0);
    }

    int ocol = lane & 15;
    int orow0 = r0 + (lane >> 4) * 4;
    int col = colBase + ocol;
    float b = bl[col];
#pragma unroll
    for (int j = 0; j < 4; ++j) {
        int ra = orow0 + j;
        int rb = ra + 16;
        if (ra < N_NODES) zout[(size_t)ra * D + col] = f2bf(acc0[j] + b);
        if (rb < N_NODES) zout[(size_t)rb * D + col] = f2bf(acc1[j] + b);
    }
}

// ---------------- fused MLP (512 threads) ----------------
__global__ __launch_bounds__(512) void mlp_fused_kernel(
        const unsigned short* __restrict__ z0,   // [N,128]
        const unsigned short* __restrict__ z1b,  // [N,128]
        const unsigned short* __restrict__ z2,   // [N,128]
        const unsigned short* __restrict__ W1T,  // [128][384]
        const float* __restrict__ b1,
        const unsigned short* __restrict__ W2T,  // [48][128]
        const float* __restrict__ b2,
        float* __restrict__ out) {
    __shared__ unsigned short zs[BR][392];   // staged A; overlaid with z1 tile later
    int tid = threadIdx.x;
    int wid = tid >> 6;
    int lane = tid & 63;
    int r0 = blockIdx.x * BR;
    int lrow = lane & 15;
    int lk8 = (lane >> 4) * 8;
    int colBase = wid * 16;

    // ---- B prefetch: 12 W1T fragments into registers (one latency, no spill)
    short8 bw[12];
#pragma unroll
    for (int kc = 0; kc < 12; ++kc) {
        bw[kc] = *(const short8*)(W1T + (size_t)(colBase + lrow) * DZ + kc * 32 + lk8);
    }

    // ---- phase 0: stage 3 bufs x (512 x 16B chunks), 1 chunk/thread/buf
    const unsigned short* zbuf[3] = {z0, z1b, z2};
#pragma unroll
    for (int b = 0; b < 3; ++b) {
        int row = tid >> 4, c8 = (tid & 15) * 8;
        int rc = min(r0 + row, N_NODES - 1);
        *(uint4*)(&zs[row][b * 128 + c8]) = *(const uint4*)(zbuf[b] + (size_t)rc * D + c8);
    }
    __syncthreads();

    // ---- phase A: 8 waves x 16-col stripes, K=384, A from LDS, B from regs
    f32x4 acc0 = (f32x4){0.f,0.f,0.f,0.f};
    f32x4 acc1 = (f32x4){0.f,0.f,0.f,0.f};
#pragma unroll
    for (int kc = 0; kc < 12; ++kc) {
        short8 aF0 = *(const short8*)(&zs[lrow][kc * 32 + lk8]);
        short8 aF1 = *(const short8*)(&zs[16 + lrow][kc * 32 + lk8]);
        acc0 = __builtin_amdgcn_mfma_f32_16x16x32_bf16(aF0, bw[kc], acc0, 0, 0, 0);
        acc1 = __builtin_amdgcn_mfma_f32_16x16x32_bf16(aF1, bw[kc], acc1, 0, 0, 0);
    }
    __syncthreads();   // all zs reads done before overlay write

    // ---- write z1 tile into zs[.][0..128) (overlay)
    int ocol = lane & 15;
    int lrow0 = (lane >> 4) * 4;
    {
        int col = colBase + ocol;
        float b = b1[col];
#pragma unroll
        for (int j = 0; j < 4; ++j) {
            zs[lrow0 + j][col] = f2bf(fmaxf(acc0[j] + b, 0.f));
            zs[16 + lrow0 + j][col] = f2bf(fmaxf(acc1[j] + b, 0.f));
        }
    }
    __syncthreads();

    // ---- phase B: waves 0,1 -> 16 rows x 48 cols each, K=128, + log-softmax
    if (wid < 2) {
        f32x4 acc[3];
#pragma unroll
        for (int t = 0; t < 3; ++t) acc[t] = (f32x4){0.f,0.f,0.f,0.f};
        int lr = wid * 16 + lrow;
#pragma unroll
        for (int kc = 0; kc < 4; ++kc) {
            short8 aF = *(const short8*)(&zs[lr][kc * 32 + lk8]);
#pragma unroll
            for (int ct = 0; ct < 3; ++ct) {
                short8 bF = *(const short8*)(W2T + (size_t)(ct * 16 + lrow) * 128 + kc * 32 + lk8);
                acc[ct] = __builtin_amdgcn_mfma_f32_16x16x32_bf16(aF, bF, acc[ct], 0, 0, 0);
            }
        }

        float b0 = b2[ocol];
        float b1v = b2[16 + ocol];
        float b2v = (ocol < 8) ? b2[32 + ocol] : 0.f;

#pragma unroll
        for (int j = 0; j < 4; ++j) {
            int orow = r0 + wid * 16 + (lane >> 4) * 4 + j;
            float v0 = acc[0][j] + b0;
            float v1 = acc[1][j] + b1v;
            float v2 = (ocol < 8) ? (acc[2][j] + b2v) : -1e30f;
            float mx = fmaxf(fmaxf(v0, v1), v2);
            mx = fmaxf(mx, __shfl_xor(mx, 1));
            mx = fmaxf(mx, __shfl_xor(mx, 2));
            mx = fmaxf(mx, __shfl_xor(mx, 4));
            mx = fmaxf(mx, __shfl_xor(mx, 8));
            float es = expf(v0 - mx) + expf(v1 - mx) + ((ocol < 8) ? expf(v2 - mx) : 0.f);
            es += __shfl_xor(es, 1);
            es += __shfl_xor(es, 2);
            es += __shfl_xor(es, 4);
            es += __shfl_xor(es, 8);
            float ls = logf(es);
            if (orow < N_NODES) {
                out[(size_t)orow * DOUT + ocol] = v0 - mx - ls;
                out[(size_t)orow * DOUT + 16 + ocol] = v1 - mx - ls;
                if (ocol < 8) out[(size_t)orow * DOUT + 32 + ocol] = v2 - mx - ls;
            }
        }
    }
}

// ---------------- launch ----------------

extern "C" void kernel_launch(void* const* d_in, const int* in_sizes, int n_in,
                              void* d_out, int out_size, void* d_ws, size_t ws_size,
                              hipStream_t stream) {
    const float* x   = (const float*)d_in[0];
    const int*   ei  = (const int*)d_in[1];
    const float* Wl  = (const float*)d_in[2];
    const float* Wr  = (const float*)d_in[3];
    const float* bl  = (const float*)d_in[4];
    const float* W1  = (const float*)d_in[5];
    const float* b1  = (const float*)d_in[6];
    const float* W2  = (const float*)d_in[7];
    const float* b2  = (const float*)d_in[8];
    float* out = (float*)d_out;

    const int E = in_sizes[1] / 2;
    const int* src = ei;
    const int* dst = ei + E;

    int CH = 2048;
    int nblk1 = (E + CH - 1) / CH;
    if (nblk1 > 512) { CH = ((E + 511) / 512 + 255) & ~255; nblk1 = (E + CH - 1) / CH; }

    char* p = (char*)d_ws;
    auto take = [&p](size_t bytes) { char* q = p; p += (bytes + 255) & ~(size_t)255; return q; };
    int* offs        = (int*)take((N_NODES + 1) * sizeof(int));
    int* H           = (int*)take((size_t)BUCKETS * nblk1 * sizeof(int));
    int* T           = (int*)take(BUCKETS * sizeof(int));
    int* bucketStart = (int*)take((BUCKETS + 1) * sizeof(int));
    unsigned int*   recs = (unsigned int*)take((size_t)E * sizeof(unsigned int));
    unsigned short* adj  = (unsigned short*)take((size_t)E * sizeof(unsigned short));
    unsigned short* xb  = (unsigned short*)take((size_t)N_NODES * D * 2);
    unsigned short* z0  = (unsigned short*)take((size_t)N_NODES * D * 2);
    unsigned short* z1  = (unsigned short*)take((size_t)N_NODES * D * 2);
    unsigned short* z2  = (unsigned short*)take((size_t)N_NODES * D * 2);
    unsigned short* WT  = (unsigned short*)take((size_t)LAYERS * 128 * 256 * 2);
    unsigned short* W1T = (unsigned short*)take((size_t)128 * 384 * 2);
    unsigned short* W2T = (unsigned short*)take((size_t)48 * 128 * 2);

    // prep: cvt + all weight packs in one kernel
    int n4 = N_NODES * D / 4;
    int prep_total = n4 + LAYERS * 128 * 256 + 128 * 384 + 48 * 128;
    prep_kernel<<<(prep_total + 255) / 256, 256, 0, stream>>>(
        x, Wl, Wr, W1, W2, xb, WT, W1T, W2T, n4);

    // CSR via counting sort (no global atomics)
    hist1_kernel<<<nblk1, 256, 0, stream>>>(dst, E, CH, nblk1, H);
    scanS_kernel<<<BUCKETS, 512, 0, stream>>>(H, nblk1, T);
    bstart_kernel<<<1, 256, 0, stream>>>(T, bucketStart, offs, E);
    scatter_kernel<<<nblk1, 256, 0, stream>>>(src, dst, E, CH, nblk1, H, bucketStart, recs);
    bucket_csr_kernel<<<BUCKETS, 256, 0, stream>>>(recs, bucketStart, offs, adj);

    int fgrid = (N_NODES + BR - 1) / BR;   // 1563

    unsigned short* zsb[3] = {z0, z1, z2};
    for (int i = 0; i < LAYERS; ++i) {
        const unsigned short* hin = (i == 0) ? xb : zsb[i - 1];
        sage_fused_kernel<<<fgrid, 512, 0, stream>>>(
            hin, offs, adj, WT + (size_t)i * 128 * 256, bl + (size_t)i * D, zsb[i]);
    }

    mlp_fused_kernel<<<fgrid, 512, 0, stream>>>(z0, z1, z2, W1T, b1, W2T, b2, out);
}

// Round 19
// 191.923 us; speedup vs baseline: 1.7451x; 1.7451x over previous
//
#include <hip/hip_runtime.h>
#include <math.h>

#define N_NODES 50000
#define D 128
#define LAYERS 3
#define DZ 384
#define DOUT 40
#define BUCKETS 196          // ceil(50000/256)
#define BR 32                // rows per block in fused kernels

typedef __attribute__((ext_vector_type(4))) float f32x4;
typedef __attribute__((ext_vector_type(8))) short short8;

static __device__ __forceinline__ unsigned short f2bf(float f) {
    unsigned int u = __float_as_uint(f);
    u += 0x7FFFu + ((u >> 16) & 1u);
    return (unsigned short)(u >> 16);
}
static __device__ __forceinline__ float bflo(unsigned int u) {
    return __uint_as_float(u << 16);
}
static __device__ __forceinline__ float bfhi(unsigned int u) {
    return __uint_as_float(u & 0xFFFF0000u);
}
static __device__ __forceinline__ void accq(float* acc, uint4 q, float wgt) {
    acc[0] = fmaf(wgt, bflo(q.x), acc[0]);
    acc[1] = fmaf(wgt, bfhi(q.x), acc[1]);
    acc[2] = fmaf(wgt, bflo(q.y), acc[2]);
    acc[3] = fmaf(wgt, bfhi(q.y), acc[3]);
    acc[4] = fmaf(wgt, bflo(q.z), acc[4]);
    acc[5] = fmaf(wgt, bfhi(q.z), acc[5]);
    acc[6] = fmaf(wgt, bflo(q.w), acc[6]);
    acc[7] = fmaf(wgt, bfhi(q.w), acc[7]);
}

// ---------------- CSR build: atomic-free counting sort (dst) ----------------

__global__ __launch_bounds__(256) void hist1_kernel(const int* __restrict__ dst, int E, int CH,
                                                    int nblk1, int* __restrict__ H) {
    __shared__ int h[BUCKETS];
    int t = threadIdx.x;
    if (t < BUCKETS) h[t] = 0;
    __syncthreads();
    int s = blockIdx.x * CH, e = min(E, s + CH);
    for (int i = s + t; i < e; i += 256) atomicAdd(&h[dst[i] >> 8], 1);
    __syncthreads();
    if (t < BUCKETS) H[t * nblk1 + blockIdx.x] = h[t];
}

__global__ __launch_bounds__(512) void scanS_kernel(int* __restrict__ H, int nblk1,
                                                    int* __restrict__ T) {
    __shared__ int s[512];
    int t = threadIdx.x, k = blockIdx.x;
    int v = (t < nblk1) ? H[k * nblk1 + t] : 0;
    s[t] = v;
    __syncthreads();
    for (int off = 1; off < 512; off <<= 1) {
        int u = (t >= off) ? s[t - off] : 0;
        __syncthreads();
        s[t] += u;
        __syncthreads();
    }
    if (t < nblk1) H[k * nblk1 + t] = s[t] - v;
    if (t == 511) T[k] = s[511];
}

__global__ __launch_bounds__(256) void bstart_kernel(const int* __restrict__ T,
                                                     int* __restrict__ bucketStart,
                                                     int* __restrict__ offs, int E) {
    __shared__ int s[256];
    int t = threadIdx.x;
    int v = (t < BUCKETS) ? T[t] : 0;
    s[t] = v;
    __syncthreads();
    for (int off = 1; off < 256; off <<= 1) {
        int u = (t >= off) ? s[t - off] : 0;
        __syncthreads();
        s[t] += u;
        __syncthreads();
    }
    if (t < BUCKETS) bucketStart[t] = s[t] - v;
    if (t == 0) { bucketStart[BUCKETS] = E; offs[N_NODES] = E; }
}

__global__ __launch_bounds__(256) void scatter_kernel(const int* __restrict__ src,
                                                      const int* __restrict__ dst, int E, int CH,
                                                      int nblk1, const int* __restrict__ H,
                                                      const int* __restrict__ bucketStart,
                                                      unsigned int* __restrict__ recs) {
    __shared__ int cur[BUCKETS];
    int t = threadIdx.x;
    if (t < BUCKETS) cur[t] = bucketStart[t] + H[t * nblk1 + blockIdx.x];
    __syncthreads();
    int s = blockIdx.x * CH, e = min(E, s + CH);
    for (int i = s + t; i < e; i += 256) {
        int d = dst[i];
        int pos = atomicAdd(&cur[d >> 8], 1);
        recs[pos] = (unsigned int)(src[i] & 0xFFFF) | ((unsigned int)(d & 255) << 16);
    }
}

__global__ __launch_bounds__(256) void bucket_csr_kernel(const unsigned int* __restrict__ recs,
                                                         const int* __restrict__ bucketStart,
                                                         int* __restrict__ offs,
                                                         unsigned short* __restrict__ adj) {
    __shared__ int h[256];
    __shared__ int sc[256];
    __shared__ int cur[256];
    int t = threadIdx.x, k = blockIdx.x;
    int bs = bucketStart[k], be = bucketStart[k + 1];
    h[t] = 0;
    __syncthreads();
    for (int i = bs + t; i < be; i += 256) atomicAdd(&h[(recs[i] >> 16) & 255], 1);
    __syncthreads();
    int v = h[t];
    sc[t] = v;
    __syncthreads();
    for (int off = 1; off < 256; off <<= 1) {
        int u = (t >= off) ? sc[t - off] : 0;
        __syncthreads();
        sc[t] += u;
        __syncthreads();
    }
    int excl = sc[t] - v;
    int node = k * 256 + t;
    if (node < N_NODES) offs[node] = bs + excl;
    cur[t] = bs + excl;
    __syncthreads();
    for (int i = bs + t; i < be; i += 256) {
        unsigned int r = recs[i];
        int pos = atomicAdd(&cur[(r >> 16) & 255], 1);
        adj[pos] = (unsigned short)(r & 0xFFFF);
    }
}

// ---------------- degree-descending node permutation (counting sort) ----------------
// key = 255 - min(deg,255); tiles of 32 get near-equal degrees -> no stragglers.

__global__ __launch_bounds__(256) void deg_hist_kernel(const int* __restrict__ offs,
                                                       int* __restrict__ HP) {
    __shared__ int h[256];
    int t = threadIdx.x;
    h[t] = 0;
    __syncthreads();
    int n = blockIdx.x * 256 + t;
    if (n < N_NODES) {
        int deg = offs[n + 1] - offs[n];
        int key = 255 - min(deg, 255);
        atomicAdd(&h[key], 1);
    }
    __syncthreads();
    HP[t * BUCKETS + blockIdx.x] = h[t];
}

__global__ __launch_bounds__(256) void bstart256_kernel(const int* __restrict__ T,
                                                        int* __restrict__ binStart) {
    __shared__ int s[256];
    int t = threadIdx.x;
    int v = T[t];
    s[t] = v;
    __syncthreads();
    for (int off = 1; off < 256; off <<= 1) {
        int u = (t >= off) ? s[t - off] : 0;
        __syncthreads();
        s[t] += u;
        __syncthreads();
    }
    binStart[t] = s[t] - v;
}

__global__ __launch_bounds__(256) void deg_scatter_kernel(const int* __restrict__ offs,
                                                          const int* __restrict__ HP,
                                                          const int* __restrict__ binStart,
                                                          int* __restrict__ perm) {
    __shared__ int cur[256];
    int t = threadIdx.x;
    cur[t] = binStart[t] + HP[t * BUCKETS + blockIdx.x];
    __syncthreads();
    int n = blockIdx.x * 256 + t;
    if (n < N_NODES) {
        int deg = offs[n + 1] - offs[n];
        int key = 255 - min(deg, 255);
        int pos = atomicAdd(&cur[key], 1);
        perm[pos] = n;
    }
}

// ---------------- fused conversions + weight packing ----------------

__global__ __launch_bounds__(256) void prep_kernel(const float* __restrict__ x,
                                                   const float* __restrict__ Wl,
                                                   const float* __restrict__ Wr,
                                                   const float* __restrict__ W1,
                                                   const float* __restrict__ W2,
                                                   unsigned short* __restrict__ xb,
                                                   unsigned short* __restrict__ WT,
                                                   unsigned short* __restrict__ W1T,
                                                   unsigned short* __restrict__ W2T,
                                                   int n4) {
    int i = blockIdx.x * blockDim.x + threadIdx.x;
    if (i < n4) {
        const float4 v = ((const float4*)x)[i];
        unsigned int lo = ((unsigned int)f2bf(v.y) << 16) | f2bf(v.x);
        unsigned int hi = ((unsigned int)f2bf(v.w) << 16) | f2bf(v.z);
        ((unsigned int*)xb)[i * 2] = lo;
        ((unsigned int*)xb)[i * 2 + 1] = hi;
        return;
    }
    int j = i - n4;
    if (j < LAYERS * 128 * 256) {
        int layer = j >> 15;
        int r = j & 32767;
        int c = r >> 8, k = r & 255;
        const float* W = (k < 128) ? (Wl + layer * 16384) : (Wr + layer * 16384);
        WT[j] = f2bf(W[(k & 127) * 128 + c]);
        return;
    }
    j -= LAYERS * 128 * 256;
    if (j < 128 * 384) {
        int c = j / 384, k = j - c * 384;
        W1T[j] = f2bf(W1[k * 128 + c]);
        return;
    }
    j -= 128 * 384;
    if (j < 48 * 128) {
        int c = j >> 7, k = j & 127;
        W2T[j] = (c < DOUT) ? f2bf(W2[k * DOUT + c]) : (unsigned short)0;
    }
}

// ---------------- fused mean-aggregate + SAGE GEMM (512 threads = 8 waves) ----------------
// Block b handles nodes perm[32b..32b+32) (degree-homogeneous tile).
// Phase 0: perml -> LDS; stage the 32 permuted h-rows.
// Phase 1: one node per 16-lane group, 8-deep unrolled gather (original-space adj).
// Phase 2: 8 waves x 16-col stripes; A from LDS, B (WT) from L2; permuted C-write.
__global__ __launch_bounds__(512) void sage_fused_kernel(
        const unsigned short* __restrict__ h,    // [N,128] prev-layer features
        const int* __restrict__ offs, const unsigned short* __restrict__ adj,
        const int* __restrict__ perm,
        const unsigned short* __restrict__ WT,   // [128][256]
        const float* __restrict__ bl,
        unsigned short* __restrict__ zout) {     // [N,128]
    __shared__ unsigned short mlds[BR][136];
    __shared__ unsigned short hlds[BR][136];
    __shared__ int perml[BR];
    int tid = threadIdx.x;
    int r0 = blockIdx.x * BR;
    int gid = tid >> 4, l16 = tid & 15;

    if (tid < BR) perml[tid] = perm[min(r0 + tid, N_NODES - 1)];
    __syncthreads();

    // ---- phase 0: stage own (permuted) rows: 512 x 16B chunks
    {
        int row = tid >> 4, c8 = (tid & 15) * 8;
        *(uint4*)(&hlds[row][c8]) = *(const uint4*)(h + (size_t)perml[row] * D + c8);
    }

    // ---- phase 1: gather, one node per 16-lane group, 8-deep
    {
        const unsigned short* hb = h + l16 * 8;
        int node = perml[gid];
        float acc[8];
#pragma unroll
        for (int j = 0; j < 8; ++j) acc[j] = 0.f;
        int s = offs[node], e = offs[node + 1];
        for (int k = s; k < e; k += 8) {
            int e1 = e - 1;
            int a[8];
#pragma unroll
            for (int j = 0; j < 8; ++j) a[j] = adj[min(k + j, e1)];
            uint4 q[8];
#pragma unroll
            for (int j = 0; j < 8; ++j) q[j] = *(const uint4*)(hb + (size_t)a[j] * D);
            accq(acc, q[0], 1.f);
#pragma unroll
            for (int j = 1; j < 8; ++j) {
                float w = (k + j < e) ? 1.f : 0.f;
                accq(acc, q[j], w);
            }
        }
        float inv = 1.f / fmaxf((float)(e - s), 1.f);
        uint4 o;
        o.x = ((unsigned int)f2bf(acc[1] * inv) << 16) | f2bf(acc[0] * inv);
        o.y = ((unsigned int)f2bf(acc[3] * inv) << 16) | f2bf(acc[2] * inv);
        o.z = ((unsigned int)f2bf(acc[5] * inv) << 16) | f2bf(acc[4] * inv);
        o.w = ((unsigned int)f2bf(acc[7] * inv) << 16) | f2bf(acc[6] * inv);
        *(uint4*)(&mlds[gid][l16 * 8]) = o;
    }
    __syncthreads();

    // ---- phase 2: GEMM. 8 waves, wave cols [wid*16, wid*16+16)
    int wid = tid >> 6;
    int lane = tid & 63;
    int lrow = lane & 15;
    int lk8 = (lane >> 4) * 8;
    int colBase = wid * 16;
    f32x4 acc0 = (f32x4){0.f,0.f,0.f,0.f};
    f32x4 acc1 = (f32x4){0.f,0.f,0.f,0.f};

#pragma unroll
    for (int kc = 0; kc < 8; ++kc) {
        short8 aF0, aF1;
        if (kc < 4) {
            aF0 = *(const short8*)(&mlds[lrow][kc * 32 + lk8]);
            aF1 = *(const short8*)(&mlds[16 + lrow][kc * 32 + lk8]);
        } else {
            aF0 = *(const short8*)(&hlds[lrow][(kc - 4) * 32 + lk8]);
            aF1 = *(const short8*)(&hlds[16 + lrow][(kc - 4) * 32 + lk8]);
        }
        short8 bF = *(const short8*)(WT + (size_t)(colBase + lrow) * 256 + kc * 32 + lk8);
        acc0 = __builtin_amdgcn_mfma_f32_16x16x32_bf16(aF0, bF, acc0, 0, 0, 0);
        acc1 = __builtin_amdgcn_mfma_f32_16x16x32_bf16(aF1, bF, acc1, 0, 0, 0);
    }

    int ocol = lane & 15;
    int tr0 = (lane >> 4) * 4;
    int col = colBase + ocol;
    float b = bl[col];
#pragma unroll
    for (int j = 0; j < 4; ++j) {
        int ra = perml[tr0 + j];
        int rb = perml[tr0 + 16 + j];
        zout[(size_t)ra * D + col] = f2bf(acc0[j] + b);
        zout[(size_t)rb * D + col] = f2bf(acc1[j] + b);
    }
}

// ---------------- fused MLP (512 threads), permuted rows ----------------
__global__ __launch_bounds__(512) void mlp_fused_kernel(
        const unsigned short* __restrict__ z0,   // [N,128]
        const unsigned short* __restrict__ z1b,  // [N,128]
        const unsigned short* __restrict__ z2,   // [N,128]
        const int* __restrict__ perm,
        const unsigned short* __restrict__ W1T,  // [128][384]
        const float* __restrict__ b1,
        const unsigned short* __restrict__ W2T,  // [48][128]
        const float* __restrict__ b2,
        float* __restrict__ out) {
    __shared__ unsigned short zs[BR][392];   // staged A; overlaid with z1 tile later
    __shared__ int perml[BR];
    int tid = threadIdx.x;
    int wid = tid >> 6;
    int lane = tid & 63;
    int r0 = blockIdx.x * BR;
    int lrow = lane & 15;
    int lk8 = (lane >> 4) * 8;
    int colBase = wid * 16;

    if (tid < BR) perml[tid] = perm[min(r0 + tid, N_NODES - 1)];

    // ---- B prefetch: 12 W1T fragments into registers
    short8 bw[12];
#pragma unroll
    for (int kc = 0; kc < 12; ++kc) {
        bw[kc] = *(const short8*)(W1T + (size_t)(colBase + lrow) * DZ + kc * 32 + lk8);
    }
    __syncthreads();

    // ---- phase 0: stage 3 bufs x (512 x 16B chunks)
    const unsigned short* zbuf[3] = {z0, z1b, z2};
#pragma unroll
    for (int b = 0; b < 3; ++b) {
        int row = tid >> 4, c8 = (tid & 15) * 8;
        *(uint4*)(&zs[row][b * 128 + c8]) = *(const uint4*)(zbuf[b] + (size_t)perml[row] * D + c8);
    }
    __syncthreads();

    // ---- phase A: 8 waves x 16-col stripes, K=384, A from LDS, B from regs
    f32x4 acc0 = (f32x4){0.f,0.f,0.f,0.f};
    f32x4 acc1 = (f32x4){0.f,0.f,0.f,0.f};
#pragma unroll
    for (int kc = 0; kc < 12; ++kc) {
        short8 aF0 = *(const short8*)(&zs[lrow][kc * 32 + lk8]);
        short8 aF1 = *(const short8*)(&zs[16 + lrow][kc * 32 + lk8]);
        acc0 = __builtin_amdgcn_mfma_f32_16x16x32_bf16(aF0, bw[kc], acc0, 0, 0, 0);
        acc1 = __builtin_amdgcn_mfma_f32_16x16x32_bf16(aF1, bw[kc], acc1, 0, 0, 0);
    }
    __syncthreads();   // all zs reads done before overlay write

    // ---- write z1 tile into zs[.][0..128) (overlay)
    int ocol = lane & 15;
    int lrow0 = (lane >> 4) * 4;
    {
        int col = colBase + ocol;
        float b = b1[col];
#pragma unroll
        for (int j = 0; j < 4; ++j) {
            zs[lrow0 + j][col] = f2bf(fmaxf(acc0[j] + b, 0.f));
            zs[16 + lrow0 + j][col] = f2bf(fmaxf(acc1[j] + b, 0.f));
        }
    }
    __syncthreads();

    // ---- phase B: waves 0,1 -> 16 rows x 48 cols each, K=128, + log-softmax
    if (wid < 2) {
        f32x4 acc[3];
#pragma unroll
        for (int t = 0; t < 3; ++t) acc[t] = (f32x4){0.f,0.f,0.f,0.f};
        int lr = wid * 16 + lrow;
#pragma unroll
        for (int kc = 0; kc < 4; ++kc) {
            short8 aF = *(const short8*)(&zs[lr][kc * 32 + lk8]);
#pragma unroll
            for (int ct = 0; ct < 3; ++ct) {
                short8 bF = *(const short8*)(W2T + (size_t)(ct * 16 + lrow) * 128 + kc * 32 + lk8);
                acc[ct] = __builtin_amdgcn_mfma_f32_16x16x32_bf16(aF, bF, acc[ct], 0, 0, 0);
            }
        }

        float b0 = b2[ocol];
        float b1v = b2[16 + ocol];
        float b2v = (ocol < 8) ? b2[32 + ocol] : 0.f;

#pragma unroll
        for (int j = 0; j < 4; ++j) {
            int tr = wid * 16 + (lane >> 4) * 4 + j;
            int orow = perml[tr];
            float v0 = acc[0][j] + b0;
            float v1 = acc[1][j] + b1v;
            float v2 = (ocol < 8) ? (acc[2][j] + b2v) : -1e30f;
            float mx = fmaxf(fmaxf(v0, v1), v2);
            mx = fmaxf(mx, __shfl_xor(mx, 1));
            mx = fmaxf(mx, __shfl_xor(mx, 2));
            mx = fmaxf(mx, __shfl_xor(mx, 4));
            mx = fmaxf(mx, __shfl_xor(mx, 8));
            float es = expf(v0 - mx) + expf(v1 - mx) + ((ocol < 8) ? expf(v2 - mx) : 0.f);
            es += __shfl_xor(es, 1);
            es += __shfl_xor(es, 2);
            es += __shfl_xor(es, 4);
            es += __shfl_xor(es, 8);
            float ls = logf(es);
            out[(size_t)orow * DOUT + ocol] = v0 - mx - ls;
            out[(size_t)orow * DOUT + 16 + ocol] = v1 - mx - ls;
            if (ocol < 8) out[(size_t)orow * DOUT + 32 + ocol] = v2 - mx - ls;
        }
    }
}

// ---------------- launch ----------------

extern "C" void kernel_launch(void* const* d_in, const int* in_sizes, int n_in,
                              void* d_out, int out_size, void* d_ws, size_t ws_size,
                              hipStream_t stream) {
    const float* x   = (const float*)d_in[0];
    const int*   ei  = (const int*)d_in[1];
    const float* Wl  = (const float*)d_in[2];
    const float* Wr  = (const float*)d_in[3];
    const float* bl  = (const float*)d_in[4];
    const float* W1  = (const float*)d_in[5];
    const float* b1  = (const float*)d_in[6];
    const float* W2  = (const float*)d_in[7];
    const float* b2  = (const float*)d_in[8];
    float* out = (float*)d_out;

    const int E = in_sizes[1] / 2;
    const int* src = ei;
    const int* dst = ei + E;

    int CH = 2048;
    int nblk1 = (E + CH - 1) / CH;
    if (nblk1 > 512) { CH = ((E + 511) / 512 + 255) & ~255; nblk1 = (E + CH - 1) / CH; }

    char* p = (char*)d_ws;
    auto take = [&p](size_t bytes) { char* q = p; p += (bytes + 255) & ~(size_t)255; return q; };
    int* offs        = (int*)take((N_NODES + 1) * sizeof(int));
    int* H           = (int*)take((size_t)BUCKETS * nblk1 * sizeof(int));
    int* T           = (int*)take(BUCKETS * sizeof(int));
    int* bucketStart = (int*)take((BUCKETS + 1) * sizeof(int));
    unsigned int*   recs = (unsigned int*)take((size_t)E * sizeof(unsigned int));
    unsigned short* adj  = (unsigned short*)take((size_t)E * sizeof(unsigned short));
    int* HP          = (int*)take((size_t)256 * BUCKETS * sizeof(int));
    int* TP          = (int*)take(256 * sizeof(int));
    int* binStart    = (int*)take(256 * sizeof(int));
    int* perm        = (int*)take((size_t)N_NODES * sizeof(int));
    unsigned short* xb  = (unsigned short*)take((size_t)N_NODES * D * 2);
    unsigned short* z0  = (unsigned short*)take((size_t)N_NODES * D * 2);
    unsigned short* z1  = (unsigned short*)take((size_t)N_NODES * D * 2);
    unsigned short* z2  = (unsigned short*)take((size_t)N_NODES * D * 2);
    unsigned short* WT  = (unsigned short*)take((size_t)LAYERS * 128 * 256 * 2);
    unsigned short* W1T = (unsigned short*)take((size_t)128 * 384 * 2);
    unsigned short* W2T = (unsigned short*)take((size_t)48 * 128 * 2);

    // prep: cvt + all weight packs in one kernel
    int n4 = N_NODES * D / 4;
    int prep_total = n4 + LAYERS * 128 * 256 + 128 * 384 + 48 * 128;
    prep_kernel<<<(prep_total + 255) / 256, 256, 0, stream>>>(
        x, Wl, Wr, W1, W2, xb, WT, W1T, W2T, n4);

    // CSR via counting sort (no global atomics)
    hist1_kernel<<<nblk1, 256, 0, stream>>>(dst, E, CH, nblk1, H);
    scanS_kernel<<<BUCKETS, 512, 0, stream>>>(H, nblk1, T);
    bstart_kernel<<<1, 256, 0, stream>>>(T, bucketStart, offs, E);
    scatter_kernel<<<nblk1, 256, 0, stream>>>(src, dst, E, CH, nblk1, H, bucketStart, recs);
    bucket_csr_kernel<<<BUCKETS, 256, 0, stream>>>(recs, bucketStart, offs, adj);

    // degree-descending permutation (counting sort over 256 keys)
    deg_hist_kernel<<<BUCKETS, 256, 0, stream>>>(offs, HP);
    scanS_kernel<<<256, 512, 0, stream>>>(HP, BUCKETS, TP);
    bstart256_kernel<<<1, 256, 0, stream>>>(TP, binStart);
    deg_scatter_kernel<<<BUCKETS, 256, 0, stream>>>(offs, HP, binStart, perm);

    int fgrid = (N_NODES + BR - 1) / BR;   // 1563

    unsigned short* zsb[3] = {z0, z1, z2};
    for (int i = 0; i < LAYERS; ++i) {
        const unsigned short* hin = (i == 0) ? xb : zsb[i - 1];
        sage_fused_kernel<<<fgrid, 512, 0, stream>>>(
            hin, offs, adj, perm, WT + (size_t)i * 128 * 256, bl + (size_t)i * D, zsb[i]);
    }

    mlp_fused_kernel<<<fgrid, 512, 0, stream>>>(z0, z1, z2, perm, W1T, b1, W2T, b2, out);
}